// Round 4
// baseline (618.149 us; speedup 1.0000x reference)
//
#include <hip/hip_runtime.h>
#include <stdint.h>

#define NN 8192
#define FD 256
#define LOG2E 1.44269504088896340736f
#define SPLIT 4
#define JSLICE (NN / SPLIT)      // 2048 j per block
#define NIT (JSLICE / 32)        // 64 iterations of 32 j

typedef __attribute__((ext_vector_type(8))) __bf16 bf16x8;
typedef __attribute__((ext_vector_type(4))) float f32x4;

__device__ __forceinline__ unsigned short f2bf(float x) {
    unsigned u = __float_as_uint(x);
    u = u + 0x7fffu + ((u >> 16) & 1u);   // RNE; no NaNs in this problem
    return (unsigned short)(u >> 16);
}
__device__ __forceinline__ bf16x8 ld_bf8(const unsigned short* p) {
    uint4 v = *(const uint4*)p;
    return __builtin_bit_cast(bf16x8, v);
}
// pack two f32 -> (bf16(b)<<16)|bf16(a) by truncation, single v_perm
__device__ __forceinline__ unsigned pack_trunc2(float a, float b) {
    return __builtin_amdgcn_perm(__float_as_uint(b), __float_as_uint(a), 0x07060302u);
}

// ---------------- Kernel 0: WbT[f][k] = bf16(W[k][f]) ----------------
__global__ __launch_bounds__(256) void wtrans_kernel(const float* __restrict__ W,
                                                     unsigned short* __restrict__ WbT) {
    int idx = blockIdx.x * 256 + threadIdx.x;   // 65536 elems
    int k = idx >> 8, f = idx & 255;
    WbT[f * 256 + k] = f2bf(W[idx]);
}

// ---------------- Kernel 1: WhT[f][i] = bf16((h@W+b)[i][f]); fused f1/f2 ----------------
__global__ __launch_bounds__(256) void gemm1_kernel(const float* __restrict__ h,
                                                    const unsigned short* __restrict__ WbT,
                                                    const float* __restrict__ bias,
                                                    const float* __restrict__ av,
                                                    unsigned short* __restrict__ WhT,
                                                    float* __restrict__ f1p,
                                                    float* __restrict__ f2p) {
    __shared__ float Wh_s[256 * 33];   // [f][i], +1 pad
    __shared__ float red_s[2 * 8 * 32];
    int t = threadIdx.x;
    int l = t & 63, w = t >> 6;
    int i0 = blockIdx.x * 32;
    int fbase = w * 64;
    int cl = l & 15, q = l >> 4;

    f32x4 acc[2][4] = {};
    const float* hA0 = h + (size_t)(i0 + cl) * FD;
    const float* hA1 = h + (size_t)(i0 + 16 + cl) * FD;

    #pragma unroll
    for (int ks = 0; ks < 8; ++ks) {
        int kk = ks * 32 + q * 8;
        union { unsigned short u[8]; bf16x8 v; } ua0, ua1;
        float4 x0 = *(const float4*)(hA0 + kk);
        float4 x1 = *(const float4*)(hA0 + kk + 4);
        float4 y0 = *(const float4*)(hA1 + kk);
        float4 y1 = *(const float4*)(hA1 + kk + 4);
        ua0.u[0]=f2bf(x0.x); ua0.u[1]=f2bf(x0.y); ua0.u[2]=f2bf(x0.z); ua0.u[3]=f2bf(x0.w);
        ua0.u[4]=f2bf(x1.x); ua0.u[5]=f2bf(x1.y); ua0.u[6]=f2bf(x1.z); ua0.u[7]=f2bf(x1.w);
        ua1.u[0]=f2bf(y0.x); ua1.u[1]=f2bf(y0.y); ua1.u[2]=f2bf(y0.z); ua1.u[3]=f2bf(y0.w);
        ua1.u[4]=f2bf(y1.x); ua1.u[5]=f2bf(y1.y); ua1.u[6]=f2bf(y1.z); ua1.u[7]=f2bf(y1.w);
        #pragma unroll
        for (int bg = 0; bg < 4; ++bg) {
            bf16x8 bF = ld_bf8(WbT + (fbase + bg * 16 + cl) * 256 + kk);
            acc[0][bg] = __builtin_amdgcn_mfma_f32_16x16x32_bf16(ua0.v, bF, acc[0][bg], 0, 0, 0);
            acc[1][bg] = __builtin_amdgcn_mfma_f32_16x16x32_bf16(ua1.v, bF, acc[1][bg], 0, 0, 0);
        }
    }

    // C layout: col = lane&15, row = (lane>>4)*4 + reg   [m89-verified]
    #pragma unroll
    for (int mt = 0; mt < 2; ++mt)
        #pragma unroll
        for (int bg = 0; bg < 4; ++bg)
            #pragma unroll
            for (int e = 0; e < 4; ++e) {
                int il = mt * 16 + q * 4 + e;
                int fl = fbase + bg * 16 + cl;
                Wh_s[fl * 33 + il] = acc[mt][bg][e] + bias[fl];
            }
    __syncthreads();
    {   // thread t owns f-row t; write 32 bf16 (i-contig) as 4x uint4
        const float* src = &Wh_s[t * 33];
        unsigned short* dst = WhT + (size_t)t * NN + i0;
        #pragma unroll
        for (int ig = 0; ig < 4; ++ig) {
            union { unsigned short u[8]; uint4 v; } p;
            #pragma unroll
            for (int e = 0; e < 8; ++e) p.u[e] = f2bf(src[ig * 8 + e]);
            *(uint4*)(dst + ig * 8) = p.v;
        }
    }
    // fused f1/f2 partials: thread t -> i = t&31, f-chunk = t>>5 (32 f's)
    {
        int i = t & 31, fc = t >> 5;
        float s1 = 0.f, s2 = 0.f;
        #pragma unroll
        for (int fo = 0; fo < 32; ++fo) {
            int f = fc * 32 + fo;
            float wv = Wh_s[f * 33 + i];
            s1 += wv * av[f];
            s2 += wv * av[256 + f];
        }
        red_s[fc * 32 + i] = s1;
        red_s[256 + fc * 32 + i] = s2;
    }
    __syncthreads();
    if (t < 32) {
        float s = 0.f;
        #pragma unroll
        for (int fc = 0; fc < 8; ++fc) s += red_s[fc * 32 + t];
        f1p[i0 + t] = s * LOG2E;
    } else if (t < 64) {
        int i = t - 32;
        float s = 0.f;
        #pragma unroll
        for (int fc = 0; fc < 8; ++fc) s += red_s[256 + fc * 32 + i];
        f2p[i0 + i] = s * LOG2E;
    }
}

// ---------------- Kernel 2: fused GAT, barrier-free, register-direct P ----------------
// Grid = 256 strips x SPLIT j-slices; block = 256 thr (4 waves), zero LDS, zero barriers.
// Wave w: row-group roff=(w>>1)*16 (16 rows), f-half fbase=(w&1)*128 (8 MFMAs/iter).
// Lane (cl=l&15, q=l>>4) computes P A-fragment in regs: row cl, cols jt*32+q*8..+7.
// P-compute redundancy x2 (per f-half); adj/f2 reads served by L1 across waves.
__global__ __launch_bounds__(256, 4) void gat_kernel(const int* __restrict__ adj,
                                                     const unsigned short* __restrict__ WhT,
                                                     const float* __restrict__ f1p,
                                                     const float* __restrict__ f2p,
                                                     float* __restrict__ num,
                                                     float* __restrict__ den) {
    int t = threadIdx.x;
    int l = t & 63, w = t >> 6;
    int strip = blockIdx.x & 255;
    int s = blockIdx.x >> 8;                 // j-slice
    int i0 = strip * 32;
    int j0 = s * JSLICE;

    int cl = l & 15, q = l >> 4;
    int roff = (w >> 1) * 16;
    int fbase = (w & 1) * 128;

    float f1v = f1p[i0 + roff + cl];
    const int* arow = adj + (size_t)(i0 + roff + cl) * NN + j0 + q * 8;
    const float* f2row = f2p + j0 + q * 8;
    const unsigned short* wb = WhT + (size_t)(fbase + cl) * NN + j0 + q * 8;

    f32x4 acc[8] = {};
    float rs = 0.f;

    #pragma unroll 2
    for (int jt = 0; jt < NIT; ++jt) {
        int jo = jt * 32;
        int4 a0 = *(const int4*)(arow + jo);
        int4 a1 = *(const int4*)(arow + jo + 4);
        float4 F0 = *(const float4*)(f2row + jo);
        float4 F1 = *(const float4*)(f2row + jo + 4);

        float fe[8] = {F0.x, F0.y, F0.z, F0.w, F1.x, F1.y, F1.z, F1.w};
        int   ae[8] = {a0.x, a0.y, a0.z, a0.w, a1.x, a1.y, a1.z, a1.w};
        float wv[8];
        #pragma unroll
        for (int e = 0; e < 8; ++e) {
            float sv = f1v + fe[e];
            sv = fmaxf(sv, 0.2f * sv);           // leaky_relu, pre-scaled by log2e
            float x = __builtin_amdgcn_exp2f(sv);
            x = ae[e] > 0 ? x : 0.f;
            rs += x;
            wv[e] = x;
        }
        union { unsigned u[4]; bf16x8 v; } af;
        af.u[0] = pack_trunc2(wv[0], wv[1]);
        af.u[1] = pack_trunc2(wv[2], wv[3]);
        af.u[2] = pack_trunc2(wv[4], wv[5]);
        af.u[3] = pack_trunc2(wv[6], wv[7]);

        #pragma unroll
        for (int bg = 0; bg < 8; ++bg) {
            bf16x8 bF = ld_bf8(wb + (size_t)(bg * 16) * NN + jo);
            acc[bg] = __builtin_amdgcn_mfma_f32_16x16x32_bf16(af.v, bF, acc[bg], 0, 0, 0);
        }
    }

    // rowsum for row cl: partials live in lanes cl, cl+16, cl+32, cl+48
    rs += __shfl_xor(rs, 16);
    rs += __shfl_xor(rs, 32);
    if ((w & 1) == 0 && l < 16)
        den[(size_t)s * NN + i0 + roff + l] = rs;

    // partial numerator: C layout row r = q*4+e, col = fbase + bg*16 + cl
    float* nrow = num + (size_t)s * NN * FD;
    #pragma unroll
    for (int e = 0; e < 4; ++e) {
        int r = roff + q * 4 + e;
        #pragma unroll
        for (int bg = 0; bg < 8; ++bg)
            nrow[(size_t)(i0 + r) * FD + fbase + bg * 16 + cl] = acc[bg][e];
    }
}

// ---------------- Kernel 3: combine j-split partials ----------------
__global__ __launch_bounds__(256) void combine_kernel(const float* __restrict__ num,
                                                      const float* __restrict__ den,
                                                      float* __restrict__ out) {
    int idx = blockIdx.x * 256 + threadIdx.x;   // 2M elems; i uniform per block
    int i = idx >> 8;
    float nsum = 0.f, dsum = 0.f;
    #pragma unroll
    for (int s = 0; s < SPLIT; ++s) {
        nsum += num[(size_t)s * NN * FD + idx];
        dsum += den[(size_t)s * NN + i];
    }
    out[idx] = nsum / dsum;
}

extern "C" void kernel_launch(void* const* d_in, const int* in_sizes, int n_in,
                              void* d_out, int out_size, void* d_ws, size_t ws_size,
                              hipStream_t stream) {
    const float* h   = (const float*)d_in[0];
    const int*   adj = (const int*)d_in[1];
    const float* W   = (const float*)d_in[2];
    const float* b   = (const float*)d_in[3];
    const float* a   = (const float*)d_in[4];
    float* out = (float*)d_out;

    char* ws = (char*)d_ws;
    unsigned short* WhT = (unsigned short*)ws;                          // 4 MB
    unsigned short* WbT = (unsigned short*)(ws + (4u << 20));           // 128 KB
    float* f1p = (float*)(ws + (4u << 20) + (128u << 10));              // 32 KB
    float* f2p = f1p + NN;                                              // 32 KB
    float* den = f2p + NN;                                              // SPLIT*NN f32 = 128 KB
    float* num = (float*)(ws + (8u << 20));                             // SPLIT*8 MB = 32 MB

    wtrans_kernel<<<256, 256, 0, stream>>>(W, WbT);
    gemm1_kernel<<<256, 256, 0, stream>>>(h, WbT, b, a, WhT, f1p, f2p);
    gat_kernel<<<256 * SPLIT, 256, 0, stream>>>(adj, WhT, f1p, f2p, num, den);
    combine_kernel<<<NN * FD / 256, 256, 0, stream>>>(num, den, out);
}

// Round 5
// 489.234 us; speedup vs baseline: 1.2635x; 1.2635x over previous
//
#include <hip/hip_runtime.h>
#include <stdint.h>

#define NN 8192
#define FD 256
#define LOG2E 1.44269504088896340736f
#define SPLIT 4
#define JSLICE (NN / SPLIT)      // 2048 j per gat block
#define NIT (JSLICE / 32)        // 64 iterations of 32 j

typedef __attribute__((ext_vector_type(8))) __bf16 bf16x8;
typedef __attribute__((ext_vector_type(4))) float f32x4;

__device__ __forceinline__ unsigned short f2bf(float x) {
    unsigned u = __float_as_uint(x);
    u = u + 0x7fffu + ((u >> 16) & 1u);   // RNE; no NaNs in this problem
    return (unsigned short)(u >> 16);
}
__device__ __forceinline__ bf16x8 ld_bf8(const unsigned short* p) {
    uint4 v = *(const uint4*)p;
    return __builtin_bit_cast(bf16x8, v);
}
// pack two f32 -> (bf16(b)<<16)|bf16(a) by truncation, single v_perm
__device__ __forceinline__ unsigned pack_trunc2(float a, float b) {
    return __builtin_amdgcn_perm(__float_as_uint(b), __float_as_uint(a), 0x07060302u);
}

// ---------------- Kernel 0: WbT[f][k] = bf16(W[k][f]) ----------------
__global__ __launch_bounds__(256) void wtrans_kernel(const float* __restrict__ W,
                                                     unsigned short* __restrict__ WbT) {
    int idx = blockIdx.x * 256 + threadIdx.x;   // 65536 elems
    int k = idx >> 8, f = idx & 255;
    WbT[f * 256 + k] = f2bf(W[idx]);
}

// ---------------- Kernel 1: adjpack — stream adj into bitmask adjB[i][jt] ----------------
// Wave w handles row i = blockIdx*4 + w. Per c-iter: 4 coalesced dword loads (256 j),
// 4 ballots -> 8 mask words, lane 0 stores 2x uint4. Pure streaming at HBM ceiling.
__global__ __launch_bounds__(256) void adjpack_kernel(const int* __restrict__ adj,
                                                      unsigned* __restrict__ adjB) {
    int t = threadIdx.x;
    int l = t & 63, w = t >> 6;
    int i = blockIdx.x * 4 + w;
    const int* arow = adj + (size_t)i * NN;
    unsigned* brow = adjB + (size_t)i * (NN / 32);
    #pragma unroll 2
    for (int c = 0; c < 32; ++c) {
        int base = c * 256;
        int v0 = arow[base + l];
        int v1 = arow[base + 64 + l];
        int v2 = arow[base + 128 + l];
        int v3 = arow[base + 192 + l];
        unsigned long long b0 = __ballot(v0 > 0);
        unsigned long long b1 = __ballot(v1 > 0);
        unsigned long long b2 = __ballot(v2 > 0);
        unsigned long long b3 = __ballot(v3 > 0);
        if (l == 0) {
            uint4 lo = make_uint4((unsigned)b0, (unsigned)(b0 >> 32),
                                  (unsigned)b1, (unsigned)(b1 >> 32));
            uint4 hi = make_uint4((unsigned)b2, (unsigned)(b2 >> 32),
                                  (unsigned)b3, (unsigned)(b3 >> 32));
            *(uint4*)(brow + c * 8) = lo;
            *(uint4*)(brow + c * 8 + 4) = hi;
        }
    }
}

// ---------------- Kernel 2: WhT-packed GEMM: PB = MFMA-B-fragment layout of (h@W+b); fused f1/f2 ----------------
// PB unit (jc, fg, lane l=(cl,q)): 8 bf16 = Wh[j = jc*32 + q*8 .. +7][f = fg*16+cl].
// gat's B-fragment load (jc,fg) is then one contiguous 1 KB wave-load.
__global__ __launch_bounds__(256) void gemm1_kernel(const float* __restrict__ h,
                                                    const unsigned short* __restrict__ WbT,
                                                    const float* __restrict__ bias,
                                                    const float* __restrict__ av,
                                                    unsigned short* __restrict__ PBu,
                                                    float* __restrict__ f1p,
                                                    float* __restrict__ f2p) {
    __shared__ float Wh_s[256 * 33];   // [f][i-local], +1 pad
    __shared__ float red_s[2 * 8 * 32];
    int t = threadIdx.x;
    int l = t & 63, w = t >> 6;
    int i0 = blockIdx.x * 32;
    int fbase = w * 64;
    int cl = l & 15, q = l >> 4;

    f32x4 acc[2][4] = {};
    const float* hA0 = h + (size_t)(i0 + cl) * FD;
    const float* hA1 = h + (size_t)(i0 + 16 + cl) * FD;

    #pragma unroll
    for (int ks = 0; ks < 8; ++ks) {
        int kk = ks * 32 + q * 8;
        union { unsigned short u[8]; bf16x8 v; } ua0, ua1;
        float4 x0 = *(const float4*)(hA0 + kk);
        float4 x1 = *(const float4*)(hA0 + kk + 4);
        float4 y0 = *(const float4*)(hA1 + kk);
        float4 y1 = *(const float4*)(hA1 + kk + 4);
        ua0.u[0]=f2bf(x0.x); ua0.u[1]=f2bf(x0.y); ua0.u[2]=f2bf(x0.z); ua0.u[3]=f2bf(x0.w);
        ua0.u[4]=f2bf(x1.x); ua0.u[5]=f2bf(x1.y); ua0.u[6]=f2bf(x1.z); ua0.u[7]=f2bf(x1.w);
        ua1.u[0]=f2bf(y0.x); ua1.u[1]=f2bf(y0.y); ua1.u[2]=f2bf(y0.z); ua1.u[3]=f2bf(y0.w);
        ua1.u[4]=f2bf(y1.x); ua1.u[5]=f2bf(y1.y); ua1.u[6]=f2bf(y1.z); ua1.u[7]=f2bf(y1.w);
        #pragma unroll
        for (int bg = 0; bg < 4; ++bg) {
            bf16x8 bF = ld_bf8(WbT + (fbase + bg * 16 + cl) * 256 + kk);
            acc[0][bg] = __builtin_amdgcn_mfma_f32_16x16x32_bf16(ua0.v, bF, acc[0][bg], 0, 0, 0);
            acc[1][bg] = __builtin_amdgcn_mfma_f32_16x16x32_bf16(ua1.v, bF, acc[1][bg], 0, 0, 0);
        }
    }

    // C layout: col = lane&15, row = (lane>>4)*4 + reg   [m89-verified]
    #pragma unroll
    for (int mt = 0; mt < 2; ++mt)
        #pragma unroll
        for (int bg = 0; bg < 4; ++bg)
            #pragma unroll
            for (int e = 0; e < 4; ++e) {
                int il = mt * 16 + q * 4 + e;
                int fl = fbase + bg * 16 + cl;
                Wh_s[fl * 33 + il] = acc[mt][bg][e] + bias[fl];
            }
    __syncthreads();
    {   // emit packed-B fragments: this block is j-chunk jc = blockIdx exactly
        size_t jcBase = (size_t)blockIdx.x * 8192;   // 16 fg * 64 lanes * 8 elems
        #pragma unroll
        for (int u = 0; u < 4; ++u) {
            int fg = u * 4 + (t >> 6);
            int ll = t & 63;
            int c2 = ll & 15, q2 = ll >> 4;
            const float* src = &Wh_s[(fg * 16 + c2) * 33 + q2 * 8];
            union { unsigned short us[8]; uint4 v; } p;
            #pragma unroll
            for (int e = 0; e < 8; ++e) p.us[e] = f2bf(src[e]);
            *(uint4*)(PBu + jcBase + fg * 512 + ll * 8) = p.v;
        }
    }
    // fused f1/f2 partials: thread t -> i = t&31, f-chunk = t>>5 (32 f's)
    {
        int i = t & 31, fc = t >> 5;
        float s1 = 0.f, s2 = 0.f;
        #pragma unroll
        for (int fo = 0; fo < 32; ++fo) {
            int f = fc * 32 + fo;
            float wv = Wh_s[f * 33 + i];
            s1 += wv * av[f];
            s2 += wv * av[256 + f];
        }
        red_s[fc * 32 + i] = s1;
        red_s[256 + fc * 32 + i] = s2;
    }
    __syncthreads();
    if (t < 32) {
        float s = 0.f;
        #pragma unroll
        for (int fc = 0; fc < 8; ++fc) s += red_s[fc * 32 + t];
        f1p[i0 + t] = s * LOG2E;
    } else if (t < 64) {
        int i = t - 32;
        float s = 0.f;
        #pragma unroll
        for (int fc = 0; fc < 8; ++fc) s += red_s[256 + fc * 32 + i];
        f2p[i0 + i] = s * LOG2E;
    }
}

// ---------------- Kernel 3: fused GAT — compute-dense, cache-resident inputs ----------------
// Grid = 128 strips x SPLIT; block = 256 thr (4 waves), no LDS, no barriers.
// Wave = 16 rows x full 256 f: per iter (32 j): 1 bitmask word (broadcast), 2 f2 float4,
// 16 contiguous 1KB B-fragment loads (PB, L2-resident), 8 exp2, 16 MFMAs. P-redundancy x1.
__global__ __launch_bounds__(256) void gat_kernel(const unsigned* __restrict__ adjB,
                                                  const unsigned short* __restrict__ PBu,
                                                  const float* __restrict__ f1p,
                                                  const float* __restrict__ f2p,
                                                  float* __restrict__ num,
                                                  float* __restrict__ den) {
    int t = threadIdx.x;
    int l = t & 63, w = t >> 6;
    int strip = blockIdx.x & 127;
    int s = blockIdx.x >> 7;
    int i0 = strip * 64 + w * 16;        // wave's 16 rows
    int j0 = s * JSLICE;
    int cl = l & 15, q = l >> 4;

    float f1v = f1p[i0 + cl];
    const unsigned* mrow = adjB + (size_t)(i0 + cl) * (NN / 32) + j0 / 32;
    const float* f2r = f2p + j0 + q * 8;
    const unsigned short* pb = PBu + (size_t)(j0 / 32) * 8192 + l * 8;

    f32x4 acc[16] = {};
    float rs = 0.f;

    #pragma unroll 1
    for (int jt = 0; jt < NIT; ++jt) {
        // ---- all loads up front, independent ----
        unsigned mw = mrow[jt];
        float4 F0 = *(const float4*)(f2r + jt * 32);
        float4 F1 = *(const float4*)(f2r + jt * 32 + 4);
        bf16x8 B[16];
        const unsigned short* pbj = pb + (size_t)jt * 8192;
        #pragma unroll
        for (int fg = 0; fg < 16; ++fg) B[fg] = ld_bf8(pbj + fg * 512);

        // ---- P fragment: row cl, cols j0 + jt*32 + q*8 + e ----
        unsigned bits = mw >> (q * 8);
        float fe[8] = {F0.x, F0.y, F0.z, F0.w, F1.x, F1.y, F1.z, F1.w};
        float wv[8];
        #pragma unroll
        for (int e = 0; e < 8; ++e) {
            float sv = f1v + fe[e];
            sv = fmaxf(sv, 0.2f * sv);           // leaky_relu, pre-scaled by log2e
            float x = __builtin_amdgcn_exp2f(sv);
            x = (bits >> e) & 1 ? x : 0.f;
            rs += x;
            wv[e] = x;
        }
        union { unsigned u[4]; bf16x8 v; } af;
        af.u[0] = pack_trunc2(wv[0], wv[1]);
        af.u[1] = pack_trunc2(wv[2], wv[3]);
        af.u[2] = pack_trunc2(wv[4], wv[5]);
        af.u[3] = pack_trunc2(wv[6], wv[7]);

        #pragma unroll
        for (int fg = 0; fg < 16; ++fg)
            acc[fg] = __builtin_amdgcn_mfma_f32_16x16x32_bf16(af.v, B[fg], acc[fg], 0, 0, 0);
    }

    // rowsum for row cl: partials in lanes cl, cl+16, cl+32, cl+48
    rs += __shfl_xor(rs, 16);
    rs += __shfl_xor(rs, 32);
    if (l < 16) den[(size_t)s * NN + i0 + l] = rs;

    // partial numerator: C layout row r = q*4+e (0..15), col = fg*16+cl
    float* nrow = num + (size_t)s * NN * FD;
    #pragma unroll
    for (int e = 0; e < 4; ++e) {
        int r = i0 + q * 4 + e;
        #pragma unroll
        for (int fg = 0; fg < 16; ++fg)
            nrow[(size_t)r * FD + fg * 16 + cl] = acc[fg][e];
    }
}

// ---------------- Kernel 4: combine j-split partials ----------------
__global__ __launch_bounds__(256) void combine_kernel(const float* __restrict__ num,
                                                      const float* __restrict__ den,
                                                      float* __restrict__ out) {
    int idx = blockIdx.x * 256 + threadIdx.x;   // 2M elems; i uniform per block
    int i = idx >> 8;
    float nsum = 0.f, dsum = 0.f;
    #pragma unroll
    for (int s = 0; s < SPLIT; ++s) {
        nsum += num[(size_t)s * NN * FD + idx];
        dsum += den[(size_t)s * NN + i];
    }
    out[idx] = nsum / dsum;
}

extern "C" void kernel_launch(void* const* d_in, const int* in_sizes, int n_in,
                              void* d_out, int out_size, void* d_ws, size_t ws_size,
                              hipStream_t stream) {
    const float* h   = (const float*)d_in[0];
    const int*   adj = (const int*)d_in[1];
    const float* W   = (const float*)d_in[2];
    const float* b   = (const float*)d_in[3];
    const float* a   = (const float*)d_in[4];
    float* out = (float*)d_out;

    char* ws = (char*)d_ws;
    unsigned short* PBu = (unsigned short*)ws;                          // 4 MB packed Wh fragments
    unsigned short* WbT = (unsigned short*)(ws + (4u << 20));           // 128 KB
    float* f1p = (float*)(ws + (4u << 20) + (128u << 10));              // 32 KB
    float* f2p = f1p + NN;                                              // 32 KB
    float* den = f2p + NN;                                              // SPLIT*NN f32 = 128 KB
    unsigned* adjB = (unsigned*)(ws + (8u << 20));                      // 8 MB bitmask
    float* num = (float*)(ws + (16u << 20));                            // SPLIT*8 MB = 32 MB

    adjpack_kernel<<<NN / 4, 256, 0, stream>>>(adj, adjB);
    wtrans_kernel<<<256, 256, 0, stream>>>(W, WbT);
    gemm1_kernel<<<256, 256, 0, stream>>>(h, WbT, b, a, PBu, f1p, f2p);
    gat_kernel<<<128 * SPLIT, 256, 0, stream>>>(adjB, PBu, f1p, f2p, num, den);
    combine_kernel<<<NN * FD / 256, 256, 0, stream>>>(num, den, out);
}

// Round 6
// 485.675 us; speedup vs baseline: 1.2728x; 1.0073x over previous
//
#include <hip/hip_runtime.h>
#include <stdint.h>

#define NN 8192
#define FD 256
#define LOG2E 1.44269504088896340736f
#define SPLIT 8
#define JSLICE (NN / SPLIT)      // 1024 j per gat block
#define NIT (JSLICE / 32)        // 32 iterations of 32 j

typedef __attribute__((ext_vector_type(8))) __bf16 bf16x8;
typedef __attribute__((ext_vector_type(4))) float f32x4;

__device__ __forceinline__ unsigned short f2bf(float x) {
    unsigned u = __float_as_uint(x);
    u = u + 0x7fffu + ((u >> 16) & 1u);   // RNE; no NaNs in this problem
    return (unsigned short)(u >> 16);
}
__device__ __forceinline__ bf16x8 ld_bf8(const unsigned short* p) {
    uint4 v = *(const uint4*)p;
    return __builtin_bit_cast(bf16x8, v);
}
// pack two f32 -> (bf16(b)<<16)|bf16(a) by truncation, single v_perm
__device__ __forceinline__ unsigned pack_trunc2(float a, float b) {
    return __builtin_amdgcn_perm(__float_as_uint(b), __float_as_uint(a), 0x07060302u);
}

// ---------------- Kernel 0: WbT[f][k] = bf16(W[k][f]) ----------------
__global__ __launch_bounds__(256) void wtrans_kernel(const float* __restrict__ W,
                                                     unsigned short* __restrict__ WbT) {
    int idx = blockIdx.x * 256 + threadIdx.x;   // 65536 elems
    int k = idx >> 8, f = idx & 255;
    WbT[f * 256 + k] = f2bf(W[idx]);
}

// ---------------- Kernel 1: adjpack — stream adj into row-major bitmask adjB[i][w] ----------------
__global__ __launch_bounds__(256) void adjpack_kernel(const int* __restrict__ adj,
                                                      unsigned* __restrict__ adjB) {
    int t = threadIdx.x;
    int l = t & 63, w = t >> 6;
    int i = blockIdx.x * 4 + w;
    const int* arow = adj + (size_t)i * NN;
    unsigned* brow = adjB + (size_t)i * (NN / 32);
    #pragma unroll 2
    for (int c = 0; c < 32; ++c) {
        int base = c * 256;
        int v0 = arow[base + l];
        int v1 = arow[base + 64 + l];
        int v2 = arow[base + 128 + l];
        int v3 = arow[base + 192 + l];
        unsigned long long b0 = __ballot(v0 > 0);
        unsigned long long b1 = __ballot(v1 > 0);
        unsigned long long b2 = __ballot(v2 > 0);
        unsigned long long b3 = __ballot(v3 > 0);
        if (l == 0) {
            uint4 lo = make_uint4((unsigned)b0, (unsigned)(b0 >> 32),
                                  (unsigned)b1, (unsigned)(b1 >> 32));
            uint4 hi = make_uint4((unsigned)b2, (unsigned)(b2 >> 32),
                                  (unsigned)b3, (unsigned)(b3 >> 32));
            *(uint4*)(brow + c * 8) = lo;
            *(uint4*)(brow + c * 8 + 4) = hi;
        }
    }
}

// ---------------- Kernel 1b: transpose bitmask: adjB_T[w][i] = adjB[i][w] ----------------
// Tile 64 i x 64 w via LDS; both sides coalesced (256 B runs).
__global__ __launch_bounds__(256) void btrans_kernel(const unsigned* __restrict__ rm,
                                                     unsigned* __restrict__ tm) {
    __shared__ unsigned tile[64 * 65];
    int t = threadIdx.x;
    int l = t & 63, r0 = t >> 6;
    int i0 = (blockIdx.x & 127) * 64;
    int w0 = (blockIdx.x >> 7) * 64;
    #pragma unroll
    for (int k = 0; k < 16; ++k) {
        int r = k * 4 + r0;
        tile[r * 65 + l] = rm[(size_t)(i0 + r) * (NN / 32) + w0 + l];
    }
    __syncthreads();
    #pragma unroll
    for (int k = 0; k < 16; ++k) {
        int wi = k * 4 + r0;
        tm[(size_t)(w0 + wi) * NN + i0 + l] = tile[l * 65 + wi];
    }
}

// ---------------- Kernel 2: PB = MFMA-B-fragment-packed (h@W+b); fused f1/f2 ----------------
// PB unit (jc, fg, lane l=(cl,q)): 8 bf16 = Wh[j = jc*32 + q*8 .. +7][f = fg*16+cl].
__global__ __launch_bounds__(256) void gemm1_kernel(const float* __restrict__ h,
                                                    const unsigned short* __restrict__ WbT,
                                                    const float* __restrict__ bias,
                                                    const float* __restrict__ av,
                                                    unsigned short* __restrict__ PBu,
                                                    float* __restrict__ f1p,
                                                    float* __restrict__ f2p) {
    __shared__ float Wh_s[256 * 33];   // [f][i-local], +1 pad
    __shared__ float red_s[2 * 8 * 32];
    int t = threadIdx.x;
    int l = t & 63, w = t >> 6;
    int i0 = blockIdx.x * 32;
    int fbase = w * 64;
    int cl = l & 15, q = l >> 4;

    f32x4 acc[2][4] = {};
    const float* hA0 = h + (size_t)(i0 + cl) * FD;
    const float* hA1 = h + (size_t)(i0 + 16 + cl) * FD;

    #pragma unroll
    for (int ks = 0; ks < 8; ++ks) {
        int kk = ks * 32 + q * 8;
        union { unsigned short u[8]; bf16x8 v; } ua0, ua1;
        float4 x0 = *(const float4*)(hA0 + kk);
        float4 x1 = *(const float4*)(hA0 + kk + 4);
        float4 y0 = *(const float4*)(hA1 + kk);
        float4 y1 = *(const float4*)(hA1 + kk + 4);
        ua0.u[0]=f2bf(x0.x); ua0.u[1]=f2bf(x0.y); ua0.u[2]=f2bf(x0.z); ua0.u[3]=f2bf(x0.w);
        ua0.u[4]=f2bf(x1.x); ua0.u[5]=f2bf(x1.y); ua0.u[6]=f2bf(x1.z); ua0.u[7]=f2bf(x1.w);
        ua1.u[0]=f2bf(y0.x); ua1.u[1]=f2bf(y0.y); ua1.u[2]=f2bf(y0.z); ua1.u[3]=f2bf(y0.w);
        ua1.u[4]=f2bf(y1.x); ua1.u[5]=f2bf(y1.y); ua1.u[6]=f2bf(y1.z); ua1.u[7]=f2bf(y1.w);
        #pragma unroll
        for (int bg = 0; bg < 4; ++bg) {
            bf16x8 bF = ld_bf8(WbT + (fbase + bg * 16 + cl) * 256 + kk);
            acc[0][bg] = __builtin_amdgcn_mfma_f32_16x16x32_bf16(ua0.v, bF, acc[0][bg], 0, 0, 0);
            acc[1][bg] = __builtin_amdgcn_mfma_f32_16x16x32_bf16(ua1.v, bF, acc[1][bg], 0, 0, 0);
        }
    }

    // C layout: col = lane&15, row = (lane>>4)*4 + reg   [m89-verified]
    #pragma unroll
    for (int mt = 0; mt < 2; ++mt)
        #pragma unroll
        for (int bg = 0; bg < 4; ++bg)
            #pragma unroll
            for (int e = 0; e < 4; ++e) {
                int il = mt * 16 + q * 4 + e;
                int fl = fbase + bg * 16 + cl;
                Wh_s[fl * 33 + il] = acc[mt][bg][e] + bias[fl];
            }
    __syncthreads();
    {   // emit packed-B fragments: this block is j-chunk jc = blockIdx exactly
        size_t jcBase = (size_t)blockIdx.x * 8192;   // 16 fg * 64 lanes * 8 elems
        #pragma unroll
        for (int u = 0; u < 4; ++u) {
            int fg = u * 4 + (t >> 6);
            int ll = t & 63;
            int c2 = ll & 15, q2 = ll >> 4;
            const float* src = &Wh_s[(fg * 16 + c2) * 33 + q2 * 8];
            union { unsigned short us[8]; uint4 v; } p;
            #pragma unroll
            for (int e = 0; e < 8; ++e) p.us[e] = f2bf(src[e]);
            *(uint4*)(PBu + jcBase + fg * 512 + ll * 8) = p.v;
        }
    }
    // fused f1/f2 partials: thread t -> i = t&31, f-chunk = t>>5 (32 f's)
    {
        int i = t & 31, fc = t >> 5;
        float s1 = 0.f, s2 = 0.f;
        #pragma unroll
        for (int fo = 0; fo < 32; ++fo) {
            int f = fc * 32 + fo;
            float wv = Wh_s[f * 33 + i];
            s1 += wv * av[f];
            s2 += wv * av[256 + f];
        }
        red_s[fc * 32 + i] = s1;
        red_s[256 + fc * 32 + i] = s2;
    }
    __syncthreads();
    if (t < 32) {
        float s = 0.f;
        #pragma unroll
        for (int fc = 0; fc < 8; ++fc) s += red_s[fc * 32 + t];
        f1p[i0 + t] = s * LOG2E;
    } else if (t < 64) {
        int i = t - 32;
        float s = 0.f;
        #pragma unroll
        for (int fc = 0; fc < 8; ++fc) s += red_s[256 + fc * 32 + i];
        f2p[i0 + i] = s * LOG2E;
    }
}

// ---------------- Kernel 3: fused GAT — 32 rows/wave share B-loads; masks+f2 in LDS ----------------
// Grid = 64 strips x SPLIT; block = 256 thr (4 waves). Wave = 32 rows (2 A-frags) x 256 f.
// Stage LDS once (1 barrier): masks (NIT x 128 rows) + f2 slice. Loop: 16 contiguous PB
// loads (only global traffic), 16 exp2, 32 MFMAs. No barriers in loop.
__global__ __launch_bounds__(256, 2) void gat_kernel(const unsigned* __restrict__ adjBT,
                                                     const unsigned short* __restrict__ PBu,
                                                     const float* __restrict__ f1p,
                                                     const float* __restrict__ f2p,
                                                     float* __restrict__ num,
                                                     float* __restrict__ den) {
    __shared__ unsigned mask_s[NIT * 128];
    __shared__ float f2_s[JSLICE];

    int t = threadIdx.x;
    int l = t & 63, w = t >> 6;
    int strip = blockIdx.x & 63;
    int s = blockIdx.x >> 6;
    int i0b = strip * 128;               // block's 128 rows
    int j0 = s * JSLICE;
    int jw0 = j0 / 32;
    int cl = l & 15, q = l >> 4;

    // ---- stage masks (transposed adjB: [w][i], coalesced) + f2 slice ----
    #pragma unroll
    for (int c = 0; c < 16; ++c) {
        int idx = c * 256 + t;           // idx = jt*128 + rl
        int jt = idx >> 7, rl = idx & 127;
        mask_s[idx] = adjBT[(size_t)(jw0 + jt) * NN + i0b + rl];
    }
    *(float4*)&f2_s[t * 4] = *(const float4*)(f2p + j0 + t * 4);
    __syncthreads();

    int rA = w * 32 + cl;                // local row, group A
    float f1vA = f1p[i0b + rA];
    float f1vB = f1p[i0b + rA + 16];
    const unsigned short* pb = PBu + (size_t)jw0 * 8192 + l * 8;

    f32x4 accA[16] = {}, accB[16] = {};
    float rsA = 0.f, rsB = 0.f;

    #pragma unroll 1
    for (int jt = 0; jt < NIT; ++jt) {
        // ---- 16 contiguous B-fragment loads (the only global traffic) ----
        bf16x8 B[16];
        const unsigned short* pbj = pb + (size_t)jt * 8192;
        #pragma unroll
        for (int fg = 0; fg < 16; ++fg) B[fg] = ld_bf8(pbj + fg * 512);

        unsigned mwA = mask_s[jt * 128 + rA];
        unsigned mwB = mask_s[jt * 128 + rA + 16];
        float4 F0 = *(const float4*)&f2_s[jt * 32 + q * 8];
        float4 F1 = *(const float4*)&f2_s[jt * 32 + q * 8 + 4];

        unsigned bA = mwA >> (q * 8), bB = mwB >> (q * 8);
        float fe[8] = {F0.x, F0.y, F0.z, F0.w, F1.x, F1.y, F1.z, F1.w};
        float wA[8], wB[8];
        #pragma unroll
        for (int e = 0; e < 8; ++e) {
            float sA = f1vA + fe[e];
            sA = fmaxf(sA, 0.2f * sA);           // leaky_relu, pre-scaled by log2e
            float xA = __builtin_amdgcn_exp2f(sA);
            xA = (bA >> e) & 1 ? xA : 0.f;
            rsA += xA; wA[e] = xA;
            float sB = f1vB + fe[e];
            sB = fmaxf(sB, 0.2f * sB);
            float xB = __builtin_amdgcn_exp2f(sB);
            xB = (bB >> e) & 1 ? xB : 0.f;
            rsB += xB; wB[e] = xB;
        }
        union { unsigned u[4]; bf16x8 v; } afA, afB;
        afA.u[0] = pack_trunc2(wA[0], wA[1]); afA.u[1] = pack_trunc2(wA[2], wA[3]);
        afA.u[2] = pack_trunc2(wA[4], wA[5]); afA.u[3] = pack_trunc2(wA[6], wA[7]);
        afB.u[0] = pack_trunc2(wB[0], wB[1]); afB.u[1] = pack_trunc2(wB[2], wB[3]);
        afB.u[2] = pack_trunc2(wB[4], wB[5]); afB.u[3] = pack_trunc2(wB[6], wB[7]);

        #pragma unroll
        for (int fg = 0; fg < 16; ++fg) {
            accA[fg] = __builtin_amdgcn_mfma_f32_16x16x32_bf16(afA.v, B[fg], accA[fg], 0, 0, 0);
            accB[fg] = __builtin_amdgcn_mfma_f32_16x16x32_bf16(afB.v, B[fg], accB[fg], 0, 0, 0);
        }
    }

    // rowsums: partials for row (cl) live in lanes cl, cl+16, cl+32, cl+48
    rsA += __shfl_xor(rsA, 16); rsA += __shfl_xor(rsA, 32);
    rsB += __shfl_xor(rsB, 16); rsB += __shfl_xor(rsB, 32);
    if (l < 16) {
        den[(size_t)s * NN + i0b + w * 32 + l] = rsA;
        den[(size_t)s * NN + i0b + w * 32 + 16 + l] = rsB;
    }

    // partial numerator: C layout row r = q*4+e, col = fg*16+cl
    float* nrow = num + (size_t)s * NN * FD;
    #pragma unroll
    for (int e = 0; e < 4; ++e) {
        int r0 = i0b + w * 32 + q * 4 + e;
        #pragma unroll
        for (int fg = 0; fg < 16; ++fg) {
            nrow[(size_t)r0 * FD + fg * 16 + cl] = accA[fg][e];
            nrow[(size_t)(r0 + 16) * FD + fg * 16 + cl] = accB[fg][e];
        }
    }
}

// ---------------- Kernel 4: combine j-split partials ----------------
__global__ __launch_bounds__(256) void combine_kernel(const float* __restrict__ num,
                                                      const float* __restrict__ den,
                                                      float* __restrict__ out) {
    int idx = blockIdx.x * 256 + threadIdx.x;   // 2M elems; i uniform per block
    int i = idx >> 8;
    float nsum = 0.f, dsum = 0.f;
    #pragma unroll
    for (int s = 0; s < SPLIT; ++s) {
        nsum += num[(size_t)s * NN * FD + idx];
        dsum += den[(size_t)s * NN + i];
    }
    out[idx] = nsum / dsum;
}

extern "C" void kernel_launch(void* const* d_in, const int* in_sizes, int n_in,
                              void* d_out, int out_size, void* d_ws, size_t ws_size,
                              hipStream_t stream) {
    const float* h   = (const float*)d_in[0];
    const int*   adj = (const int*)d_in[1];
    const float* W   = (const float*)d_in[2];
    const float* b   = (const float*)d_in[3];
    const float* a   = (const float*)d_in[4];
    float* out = (float*)d_out;

    char* ws = (char*)d_ws;
    unsigned short* PBu = (unsigned short*)ws;                          // 4 MB packed Wh fragments
    unsigned short* WbT = (unsigned short*)(ws + (4u << 20));           // 128 KB
    float* f1p = (float*)(ws + (4u << 20) + (128u << 10));              // 32 KB
    float* f2p = f1p + NN;                                              // 32 KB
    float* den = f2p + NN;                                              // SPLIT*NN f32 = 256 KB
    unsigned* adjB  = (unsigned*)(ws + (8u << 20));                     // 8 MB row-major bitmask
    unsigned* adjBT = (unsigned*)(ws + (16u << 20));                    // 8 MB transposed bitmask
    float* num = (float*)(ws + (24u << 20));                            // SPLIT*8 MB = 64 MB

    adjpack_kernel<<<NN / 4, 256, 0, stream>>>(adj, adjB);
    wtrans_kernel<<<256, 256, 0, stream>>>(W, WbT);
    btrans_kernel<<<512, 256, 0, stream>>>(adjB, adjBT);
    gemm1_kernel<<<256, 256, 0, stream>>>(h, WbT, b, a, PBu, f1p, f2p);
    gat_kernel<<<64 * SPLIT, 256, 0, stream>>>(adjBT, PBu, f1p, f2p, num, den);
    combine_kernel<<<NN * FD / 256, 256, 0, stream>>>(num, den, out);
}

// Round 7
// 456.863 us; speedup vs baseline: 1.3530x; 1.0631x over previous
//
#include <hip/hip_runtime.h>
#include <stdint.h>

#define NN 8192
#define FD 256
#define LOG2E 1.44269504088896340736f
#define SPLIT 8
#define JSLICE (NN / SPLIT)      // 1024 j per gat block
#define NIT (JSLICE / 32)        // 32 iterations of 32 j
#define NPH (NIT / 2)            // 16 double-buffer phases (2 iters each)

typedef __attribute__((ext_vector_type(8))) __bf16 bf16x8;
typedef __attribute__((ext_vector_type(4))) float f32x4;

__device__ __forceinline__ unsigned short f2bf(float x) {
    unsigned u = __float_as_uint(x);
    u = u + 0x7fffu + ((u >> 16) & 1u);   // RNE; no NaNs in this problem
    return (unsigned short)(u >> 16);
}
__device__ __forceinline__ bf16x8 ld_bf8(const unsigned short* p) {
    uint4 v = *(const uint4*)p;
    return __builtin_bit_cast(bf16x8, v);
}
// pack two f32 -> (bf16(b)<<16)|bf16(a) by truncation, single v_perm
__device__ __forceinline__ unsigned pack_trunc2(float a, float b) {
    return __builtin_amdgcn_perm(__float_as_uint(b), __float_as_uint(a), 0x07060302u);
}
// Non-sinkable async global->LDS, 16 B/lane. HW uses wave-uniform LDS base + lane*16.
__device__ __forceinline__ void async_ld16(const void* g, void* lds) {
    __builtin_amdgcn_global_load_lds(
        (const __attribute__((address_space(1))) void*)g,
        (__attribute__((address_space(3))) void*)lds, 16, 0, 0);
}

// ---------------- Kernel 0: WbT[f][k] = bf16(W[k][f]) ----------------
__global__ __launch_bounds__(256) void wtrans_kernel(const float* __restrict__ W,
                                                     unsigned short* __restrict__ WbT) {
    int idx = blockIdx.x * 256 + threadIdx.x;   // 65536 elems
    int k = idx >> 8, f = idx & 255;
    WbT[f * 256 + k] = f2bf(W[idx]);
}

// ---------------- Kernel 1: adjpack — stream adj into row-major bitmask adjB[i][w] ----------------
__global__ __launch_bounds__(256) void adjpack_kernel(const int* __restrict__ adj,
                                                      unsigned* __restrict__ adjB) {
    int t = threadIdx.x;
    int l = t & 63, w = t >> 6;
    int i = blockIdx.x * 4 + w;
    const int* arow = adj + (size_t)i * NN;
    unsigned* brow = adjB + (size_t)i * (NN / 32);
    #pragma unroll 2
    for (int c = 0; c < 32; ++c) {
        int base = c * 256;
        int v0 = arow[base + l];
        int v1 = arow[base + 64 + l];
        int v2 = arow[base + 128 + l];
        int v3 = arow[base + 192 + l];
        unsigned long long b0 = __ballot(v0 > 0);
        unsigned long long b1 = __ballot(v1 > 0);
        unsigned long long b2 = __ballot(v2 > 0);
        unsigned long long b3 = __ballot(v3 > 0);
        if (l == 0) {
            uint4 lo = make_uint4((unsigned)b0, (unsigned)(b0 >> 32),
                                  (unsigned)b1, (unsigned)(b1 >> 32));
            uint4 hi = make_uint4((unsigned)b2, (unsigned)(b2 >> 32),
                                  (unsigned)b3, (unsigned)(b3 >> 32));
            *(uint4*)(brow + c * 8) = lo;
            *(uint4*)(brow + c * 8 + 4) = hi;
        }
    }
}

// ---------------- Kernel 1b: transpose bitmask: adjB_T[w][i] = adjB[i][w] ----------------
__global__ __launch_bounds__(256) void btrans_kernel(const unsigned* __restrict__ rm,
                                                     unsigned* __restrict__ tm) {
    __shared__ unsigned tile[64 * 65];
    int t = threadIdx.x;
    int l = t & 63, r0 = t >> 6;
    int i0 = (blockIdx.x & 127) * 64;
    int w0 = (blockIdx.x >> 7) * 64;
    #pragma unroll
    for (int k = 0; k < 16; ++k) {
        int r = k * 4 + r0;
        tile[r * 65 + l] = rm[(size_t)(i0 + r) * (NN / 32) + w0 + l];
    }
    __syncthreads();
    #pragma unroll
    for (int k = 0; k < 16; ++k) {
        int wi = k * 4 + r0;
        tm[(size_t)(w0 + wi) * NN + i0 + l] = tile[l * 65 + wi];
    }
}

// ---------------- Kernel 2: PB = MFMA-B-fragment-packed (h@W+b); fused f1/f2 ----------------
// PB unit (jc, fg, lane l=(cl,q)): 8 bf16 = Wh[j = jc*32 + q*8 .. +7][f = fg*16+cl].
__global__ __launch_bounds__(256) void gemm1_kernel(const float* __restrict__ h,
                                                    const unsigned short* __restrict__ WbT,
                                                    const float* __restrict__ bias,
                                                    const float* __restrict__ av,
                                                    unsigned short* __restrict__ PBu,
                                                    float* __restrict__ f1p,
                                                    float* __restrict__ f2p) {
    __shared__ float Wh_s[256 * 33];   // [f][i-local], +1 pad
    __shared__ float red_s[2 * 8 * 32];
    int t = threadIdx.x;
    int l = t & 63, w = t >> 6;
    int i0 = blockIdx.x * 32;
    int fbase = w * 64;
    int cl = l & 15, q = l >> 4;

    f32x4 acc[2][4] = {};
    const float* hA0 = h + (size_t)(i0 + cl) * FD;
    const float* hA1 = h + (size_t)(i0 + 16 + cl) * FD;

    #pragma unroll
    for (int ks = 0; ks < 8; ++ks) {
        int kk = ks * 32 + q * 8;
        union { unsigned short u[8]; bf16x8 v; } ua0, ua1;
        float4 x0 = *(const float4*)(hA0 + kk);
        float4 x1 = *(const float4*)(hA0 + kk + 4);
        float4 y0 = *(const float4*)(hA1 + kk);
        float4 y1 = *(const float4*)(hA1 + kk + 4);
        ua0.u[0]=f2bf(x0.x); ua0.u[1]=f2bf(x0.y); ua0.u[2]=f2bf(x0.z); ua0.u[3]=f2bf(x0.w);
        ua0.u[4]=f2bf(x1.x); ua0.u[5]=f2bf(x1.y); ua0.u[6]=f2bf(x1.z); ua0.u[7]=f2bf(x1.w);
        ua1.u[0]=f2bf(y0.x); ua1.u[1]=f2bf(y0.y); ua1.u[2]=f2bf(y0.z); ua1.u[3]=f2bf(y0.w);
        ua1.u[4]=f2bf(y1.x); ua1.u[5]=f2bf(y1.y); ua1.u[6]=f2bf(y1.z); ua1.u[7]=f2bf(y1.w);
        #pragma unroll
        for (int bg = 0; bg < 4; ++bg) {
            bf16x8 bF = ld_bf8(WbT + (fbase + bg * 16 + cl) * 256 + kk);
            acc[0][bg] = __builtin_amdgcn_mfma_f32_16x16x32_bf16(ua0.v, bF, acc[0][bg], 0, 0, 0);
            acc[1][bg] = __builtin_amdgcn_mfma_f32_16x16x32_bf16(ua1.v, bF, acc[1][bg], 0, 0, 0);
        }
    }

    // C layout: col = lane&15, row = (lane>>4)*4 + reg   [m89-verified]
    #pragma unroll
    for (int mt = 0; mt < 2; ++mt)
        #pragma unroll
        for (int bg = 0; bg < 4; ++bg)
            #pragma unroll
            for (int e = 0; e < 4; ++e) {
                int il = mt * 16 + q * 4 + e;
                int fl = fbase + bg * 16 + cl;
                Wh_s[fl * 33 + il] = acc[mt][bg][e] + bias[fl];
            }
    __syncthreads();
    {   // emit packed-B fragments: this block is j-chunk jc = blockIdx exactly
        size_t jcBase = (size_t)blockIdx.x * 8192;   // 16 fg * 64 lanes * 8 elems
        #pragma unroll
        for (int u = 0; u < 4; ++u) {
            int fg = u * 4 + (t >> 6);
            int ll = t & 63;
            int c2 = ll & 15, q2 = ll >> 4;
            const float* src = &Wh_s[(fg * 16 + c2) * 33 + q2 * 8];
            union { unsigned short us[8]; uint4 v; } p;
            #pragma unroll
            for (int e = 0; e < 8; ++e) p.us[e] = f2bf(src[e]);
            *(uint4*)(PBu + jcBase + fg * 512 + ll * 8) = p.v;
        }
    }
    // fused f1/f2 partials: thread t -> i = t&31, f-chunk = t>>5 (32 f's)
    {
        int i = t & 31, fc = t >> 5;
        float s1 = 0.f, s2 = 0.f;
        #pragma unroll
        for (int fo = 0; fo < 32; ++fo) {
            int f = fc * 32 + fo;
            float wv = Wh_s[f * 33 + i];
            s1 += wv * av[f];
            s2 += wv * av[256 + f];
        }
        red_s[fc * 32 + i] = s1;
        red_s[256 + fc * 32 + i] = s2;
    }
    __syncthreads();
    if (t < 32) {
        float s = 0.f;
        #pragma unroll
        for (int fc = 0; fc < 8; ++fc) s += red_s[fc * 32 + t];
        f1p[i0 + t] = s * LOG2E;
    } else if (t < 64) {
        int i = t - 32;
        float s = 0.f;
        #pragma unroll
        for (int fc = 0; fc < 8; ++fc) s += red_s[256 + fc * 32 + i];
        f2p[i0 + i] = s * LOG2E;
    }
}

// ---------------- Kernel 3: fused GAT — LDS-staged B (global_load_lds dbuf), 1 barrier / 2 iters ----------------
// Grid = 128 strips x SPLIT; block = 256 thr (4 waves), 64 rows x 1024 j.
// Prologue: masks (NIT x 64 rows) + f2 slice -> LDS once. Loop: phase = 2 iters; stage next
// 32 KB PB chunk via async global->LDS into buf^1, compute from buf (16 ds_read_b128 +
// 8 exp2 + 16 MFMA per wave-iter). Only global traffic in loop = the async staging.
__global__ __launch_bounds__(256, 2) void gat_kernel(const unsigned* __restrict__ adjBT,
                                                     const unsigned short* __restrict__ PBu,
                                                     const float* __restrict__ f1p,
                                                     const float* __restrict__ f2p,
                                                     float* __restrict__ num,
                                                     float* __restrict__ den) {
    __shared__ __align__(16) unsigned short Bs[2][2 * 8192];   // 64 KB: [buf][iter-in-phase * 8192 + ...]
    __shared__ unsigned mask_s[NIT * 64];                      // 8 KB
    __shared__ float f2_s[JSLICE];                             // 4 KB

    int t = threadIdx.x;
    int l = t & 63, w = t >> 6;
    int strip = blockIdx.x & 127;
    int s = blockIdx.x >> 7;
    int i0b = strip * 64;                // block's 64 rows
    int j0 = s * JSLICE;
    int jw0 = j0 / 32;
    int cl = l & 15, q = l >> 4;

    // ---- stage masks (adjBT[w][i], coalesced) + f2 slice, once ----
    #pragma unroll
    for (int c = 0; c < 8; ++c) {
        int idx = c * 256 + t;           // idx = jt*64 + rl
        int jt = idx >> 6, rl = idx & 63;
        mask_s[idx] = adjBT[(size_t)(jw0 + jt) * NN + i0b + rl];
    }
    *(float4*)&f2_s[t * 4] = *(const float4*)(f2p + j0 + t * 4);

    const char* pbBase = (const char*)(PBu + (size_t)jw0 * 8192);  // byte base of slice
    // stage phase 0 (iters 0,1 = 32 KB): thread t covers bytes k*4096 + t*16
    #pragma unroll
    for (int k = 0; k < 8; ++k)
        async_ld16(pbBase + k * 4096 + t * 16, (char*)&Bs[0][0] + k * 4096 + t * 16);

    int rowi = i0b + w * 16 + cl;        // wave w owns rows i0b + w*16 .. +15
    float f1v = f1p[rowi];

    f32x4 acc[16] = {};
    float rs = 0.f;

    #pragma unroll 1
    for (int ph = 0; ph < NPH; ++ph) {
        __syncthreads();   // drains async staging of buf[ph&1] (+ prologue LDS on ph=0)
        if (ph + 1 < NPH) {
            const char* src = pbBase + (size_t)(2 * ph + 2) * 16384;
            char* dst = (char*)&Bs[(ph + 1) & 1][0];
            #pragma unroll
            for (int k = 0; k < 8; ++k)
                async_ld16(src + k * 4096 + t * 16, dst + k * 4096 + t * 16);
        }
        const unsigned short* bb = &Bs[ph & 1][0];
        #pragma unroll
        for (int u = 0; u < 2; ++u) {
            int jt = 2 * ph + u;
            unsigned mw = mask_s[jt * 64 + w * 16 + cl];
            float4 F0 = *(const float4*)&f2_s[jt * 32 + q * 8];
            float4 F1 = *(const float4*)&f2_s[jt * 32 + q * 8 + 4];

            unsigned bits = mw >> (q * 8);
            float fe[8] = {F0.x, F0.y, F0.z, F0.w, F1.x, F1.y, F1.z, F1.w};
            float wv[8];
            #pragma unroll
            for (int e = 0; e < 8; ++e) {
                float sv = f1v + fe[e];
                sv = fmaxf(sv, 0.2f * sv);           // leaky_relu, pre-scaled by log2e
                float x = __builtin_amdgcn_exp2f(sv);
                x = (bits >> e) & 1 ? x : 0.f;
                rs += x;
                wv[e] = x;
            }
            union { unsigned uu[4]; bf16x8 v; } af;
            af.uu[0] = pack_trunc2(wv[0], wv[1]);
            af.uu[1] = pack_trunc2(wv[2], wv[3]);
            af.uu[2] = pack_trunc2(wv[4], wv[5]);
            af.uu[3] = pack_trunc2(wv[6], wv[7]);

            const unsigned short* bu = bb + u * 8192 + l * 8;
            #pragma unroll
            for (int fg = 0; fg < 16; ++fg) {
                bf16x8 B = ld_bf8(bu + fg * 512);
                acc[fg] = __builtin_amdgcn_mfma_f32_16x16x32_bf16(af.v, B, acc[fg], 0, 0, 0);
            }
        }
    }

    // rowsum for row cl of wave's group: partials in lanes cl, cl+16, cl+32, cl+48
    rs += __shfl_xor(rs, 16);
    rs += __shfl_xor(rs, 32);
    if (l < 16) den[(size_t)s * NN + i0b + w * 16 + l] = rs;

    // partial numerator: C layout row r = q*4+e, col = fg*16+cl
    float* nrow = num + (size_t)s * NN * FD;
    #pragma unroll
    for (int e = 0; e < 4; ++e) {
        int r = i0b + w * 16 + q * 4 + e;
        #pragma unroll
        for (int fg = 0; fg < 16; ++fg)
            nrow[(size_t)r * FD + fg * 16 + cl] = acc[fg][e];
    }
}

// ---------------- Kernel 4: combine j-split partials ----------------
__global__ __launch_bounds__(256) void combine_kernel(const float* __restrict__ num,
                                                      const float* __restrict__ den,
                                                      float* __restrict__ out) {
    int idx = blockIdx.x * 256 + threadIdx.x;   // 2M elems; i uniform per block
    int i = idx >> 8;
    float nsum = 0.f, dsum = 0.f;
    #pragma unroll
    for (int s = 0; s < SPLIT; ++s) {
        nsum += num[(size_t)s * NN * FD + idx];
        dsum += den[(size_t)s * NN + i];
    }
    out[idx] = nsum / dsum;
}

extern "C" void kernel_launch(void* const* d_in, const int* in_sizes, int n_in,
                              void* d_out, int out_size, void* d_ws, size_t ws_size,
                              hipStream_t stream) {
    const float* h   = (const float*)d_in[0];
    const int*   adj = (const int*)d_in[1];
    const float* W   = (const float*)d_in[2];
    const float* b   = (const float*)d_in[3];
    const float* a   = (const float*)d_in[4];
    float* out = (float*)d_out;

    char* ws = (char*)d_ws;
    unsigned short* PBu = (unsigned short*)ws;                          // 4 MB packed Wh fragments
    unsigned short* WbT = (unsigned short*)(ws + (4u << 20));           // 128 KB
    float* f1p = (float*)(ws + (4u << 20) + (128u << 10));              // 32 KB
    float* f2p = f1p + NN;                                              // 32 KB
    float* den = f2p + NN;                                              // SPLIT*NN f32 = 256 KB
    unsigned* adjB  = (unsigned*)(ws + (8u << 20));                     // 8 MB row-major bitmask
    unsigned* adjBT = (unsigned*)(ws + (16u << 20));                    // 8 MB transposed bitmask
    float* num = (float*)(ws + (24u << 20));                            // SPLIT*8 MB = 64 MB

    adjpack_kernel<<<NN / 4, 256, 0, stream>>>(adj, adjB);
    wtrans_kernel<<<256, 256, 0, stream>>>(W, WbT);
    btrans_kernel<<<512, 256, 0, stream>>>(adjB, adjBT);
    gemm1_kernel<<<256, 256, 0, stream>>>(h, WbT, b, a, PBu, f1p, f2p);
    gat_kernel<<<128 * SPLIT, 256, 0, stream>>>(adjBT, PBu, f1p, f2p, num, den);
    combine_kernel<<<NN * FD / 256, 256, 0, stream>>>(num, den, out);
}